// Round 18
// baseline (64.039 us; speedup 1.0000x reference)
//
#include <hip/hip_runtime.h>
#include <hip/hip_bf16.h>

#define N_ROWS 32768
#define K_DIM 512
#define OUT_DIM 512
#define N_TYPES 8
#define BM 64
#define BN 256
#define BK 64
#define TPB 512             // row-tiles per type (fixed segment: 512*64 = N)

typedef __attribute__((ext_vector_type(8))) short bf16x8;
typedef __attribute__((ext_vector_type(4))) float f32x4;

__device__ inline ushort f2bf(float f) {
    __hip_bfloat16 h = __float2bfloat16(f);
    return *reinterpret_cast<ushort*>(&h);
}

__device__ inline void gload_lds16(const void* g, void* l) {
    __builtin_amdgcn_global_load_lds(
        (const __attribute__((address_space(1))) void*)g,
        (__attribute__((address_space(3))) void*)l, 16, 0, 0);
}

// meta[0..7] = per-type cursors; final value after k_fill = per-type count.
// row_ids: fixed 1-MB layout, segment t at [t*N_ROWS, ...), rest stays -1.
__global__ void k_fill(const int* __restrict__ x_type, int* meta, int* __restrict__ row_ids) {
    __shared__ int lcnt[N_TYPES];
    __shared__ int lbase[N_TYPES];
    if (threadIdx.x < N_TYPES) lcnt[threadIdx.x] = 0;
    __syncthreads();
    int i = blockIdx.x * 256 + threadIdx.x;
    int t = x_type[i];
    int lpos = atomicAdd(&lcnt[t], 1);
    __syncthreads();
    if (threadIdx.x < N_TYPES)
        lbase[threadIdx.x] = (lcnt[threadIdx.x] > 0)
            ? atomicAdd(&meta[threadIdx.x], lcnt[threadIdx.x]) : 0;
    __syncthreads();
    row_ids[(size_t)t * N_ROWS + lbase[t] + lpos] = i;
}

// W[t][k][c] fp32 -> Wt[t][c][k] bf16   (64x64 tiles through LDS)
__global__ void k_wt(const float* __restrict__ W, ushort* __restrict__ Wt) {
    __shared__ float tile[64][65];
    int t = blockIdx.x, kb = blockIdx.y, cb = blockIdx.z;
    const float* src = W + (size_t)t * K_DIM * OUT_DIM + (size_t)kb * 64 * OUT_DIM + cb * 64;
    #pragma unroll
    for (int j = 0; j < 16; ++j) {
        int idx = threadIdx.x + j * 256;
        int r = idx >> 6, c = idx & 63;
        tile[r][c] = src[(size_t)r * OUT_DIM + c];
    }
    __syncthreads();
    ushort* dst = Wt + (size_t)t * OUT_DIM * K_DIM + (size_t)(cb * 64) * K_DIM + kb * 64;
    #pragma unroll
    for (int j = 0; j < 16; ++j) {
        int idx = threadIdx.x + j * 256;
        int cc = idx >> 6, kk = idx & 63;
        dst[(size_t)cc * K_DIM + kk] = f2bf(tile[kk][cc]);
    }
}

// r14 champion (62.1 us) with ONE change: rids moved out of LDS so the block
// uses EXACTLY 40960 B (8192 As + 32768 Bs) -> 4 x 40960 = 163840 = 160 KiB
// -> 4 blocks/CU resident (was 3 at 41472 B).  sa_rid is a direct coalesced
// global read; epilogue row-ids are 16-lane-broadcast global reads (L2-hot).
// Everything else identical: 64x256 tile, 8 waves of 32x64 (acc[2][4]),
// BK=64 single-buffered, involution swizzle (0 conflicts), B staged by
// global_load_lds with involution on SOURCE (rule #21), thin A-stage
// (8 fp32->bf16 per thread), row-fastest grid for L3 absorption.
__global__ __launch_bounds__(512, 4) void k_gemm17(
    const float* __restrict__ x, const ushort* __restrict__ Wt,
    const int* __restrict__ meta, const int* __restrict__ row_ids,
    float* __restrict__ out) {

    __shared__ ushort As[BM * BK];   // 8192 B,  [row][64k], 128 B/row
    __shared__ ushort Bs[BN * BK];   // 32768 B, [col][64k], 128 B/col-row

    int b = blockIdx.x;              // 0..4095; row-tiles fastest
    int type = b >> 9;
    int r0 = (b & (TPB - 1)) * BM;
    if (r0 >= meta[type]) return;    // empty tile

    size_t seg = (size_t)type * N_ROWS + r0;

    int tid = threadIdx.x;
    int wave = tid >> 6, lane = tid & 63;

    int c0 = blockIdx.y * BN;
    const ushort* Wtt = Wt + (size_t)type * OUT_DIM * K_DIM + (size_t)c0 * K_DIM;

    // ---- A staging role: 8 threads/row, 8 elems (32 B fp32) each ----
    int sa_row  = tid >> 3;
    int sa_slot = tid & 7;           // 16-B bf16 granule within 128-B row
    int sa_rid  = row_ids[seg + sa_row];   // coalesced (8 thr/address)
    const float* sa_src = x + (size_t)max(sa_rid, 0) * K_DIM + sa_slot * 8;
    int sa_byte = (sa_row * 128 + sa_slot * 16) ^ ((sa_row & 7) << 4);

    // ---- B staging role: chunk = 8 cols x 128 B (1 KB); lane -> (col,pos);
    //      source granule = pos ^ (col&7)  (involution on SOURCE) ----
    int sb_colgrp = lane >> 3;                               // 0..7
    int sb_koff   = (((lane & 7) * 16) ^ (sb_colgrp << 4)) >> 1;  // elems

    int wrb = (wave >> 2) * 32;      // wave row base (0/32)
    int wcb = (wave & 3) * 64;       // wave col base (0..192)
    int lrow = lane & 15;
    int lkb16 = (lane >> 4) * 16;    // 16-B k-fragment offset

    f32x4 acc[2][4] = {};

    #pragma unroll 1
    for (int kk = 0; kk < K_DIM; kk += BK) {
        // stage B: 4 chunks/wave, 1 KB each (8 cols x 128 B)
        #pragma unroll
        for (int j = 0; j < 4; ++j) {
            int chunk = wave * 4 + j;
            int col = chunk * 8 + sb_colgrp;
            gload_lds16(Wtt + (size_t)col * K_DIM + kk + sb_koff,
                        (char*)Bs + chunk * 1024);
        }
        // stage A: load 8 fp32, convert, swizzled ds_write
        {
            ushort tmp[8] = {0, 0, 0, 0, 0, 0, 0, 0};
            if (sa_rid >= 0) {
                float4 v0 = *reinterpret_cast<const float4*>(sa_src + kk);
                float4 v1 = *reinterpret_cast<const float4*>(sa_src + kk + 4);
                tmp[0] = f2bf(v0.x); tmp[1] = f2bf(v0.y); tmp[2] = f2bf(v0.z); tmp[3] = f2bf(v0.w);
                tmp[4] = f2bf(v1.x); tmp[5] = f2bf(v1.y); tmp[6] = f2bf(v1.z); tmp[7] = f2bf(v1.w);
            }
            *reinterpret_cast<uint4*>((char*)As + sa_byte) = *reinterpret_cast<const uint4*>(tmp);
        }
        __syncthreads();

        #pragma unroll
        for (int s = 0; s < 2; ++s) {
            bf16x8 af[2], bfr[4];
            #pragma unroll
            for (int mi = 0; mi < 2; ++mi) {
                int row = wrb + mi * 16 + lrow;
                int byte = (row * 128 + s * 64 + lkb16) ^ ((row & 7) << 4);
                af[mi] = *reinterpret_cast<const bf16x8*>((const char*)As + byte);
            }
            #pragma unroll
            for (int ni = 0; ni < 4; ++ni) {
                int col = wcb + ni * 16 + lrow;
                int byte = (col * 128 + s * 64 + lkb16) ^ ((col & 7) << 4);
                bfr[ni] = *reinterpret_cast<const bf16x8*>((const char*)Bs + byte);
            }
            #pragma unroll
            for (int mi = 0; mi < 2; ++mi)
                #pragma unroll
                for (int ni = 0; ni < 4; ++ni)
                    acc[mi][ni] = __builtin_amdgcn_mfma_f32_16x16x32_bf16(
                        af[mi], bfr[ni], acc[mi][ni], 0, 0, 0);
        }
        __syncthreads();
    }

    // epilogue: D row = (lane>>4)*4 + rr, col = lane&15
    // row-ids read directly from global: address shared by 16 lanes -> broadcast
    int rgrp = (lane >> 4) * 4;
    #pragma unroll
    for (int mi = 0; mi < 2; ++mi) {
        #pragma unroll
        for (int rr = 0; rr < 4; ++rr) {
            int lr = wrb + mi * 16 + rgrp + rr;
            int gr = row_ids[seg + lr];
            if (gr >= 0) {
                float* dst = out + (size_t)gr * OUT_DIM + c0 + wcb;
                #pragma unroll
                for (int ni = 0; ni < 4; ++ni)
                    dst[ni * 16 + lrow] = acc[mi][ni][rr];
            }
        }
    }
}

extern "C" void kernel_launch(void* const* d_in, const int* in_sizes, int n_in,
                              void* d_out, int out_size, void* d_ws, size_t ws_size,
                              hipStream_t stream) {
    const float* x      = (const float*)d_in[0];
    const int*   x_type = (const int*)d_in[1];
    const float* W      = (const float*)d_in[2];
    float* out          = (float*)d_out;

    // ws layout: meta (256 B) | row_ids (8*N ints = 1 MB) | Wt (4 MB bf16)
    char* ws = (char*)d_ws;
    size_t off_rids = 256;
    size_t off_wt   = off_rids + sizeof(int) * (size_t)N_TYPES * N_ROWS;
    int* meta    = (int*)ws;
    int* row_ids = (int*)(ws + off_rids);
    ushort* Wt   = (ushort*)(ws + off_wt);

    hipMemsetAsync(meta, 0, sizeof(int) * N_TYPES, stream);
    hipMemsetAsync(row_ids, 0xFF, sizeof(int) * (size_t)N_TYPES * N_ROWS, stream);
    k_fill<<<N_ROWS / 256, 256, 0, stream>>>(x_type, meta, row_ids);

    dim3 wgrid(N_TYPES, K_DIM / 64, OUT_DIM / 64);
    k_wt<<<wgrid, 256, 0, stream>>>(W, Wt);

    // row-tiles fastest: the second column pass over x comes a full pass
    // later -> L3-absorbed (r6/r12/r14 evidence: ~82-85 MB FETCH)
    dim3 ggrid(N_TYPES * TPB, OUT_DIM / BN);
    k_gemm17<<<ggrid, 512, 0, stream>>>(x, Wt, meta, row_ids, out);
}

// Round 19
// 56.950 us; speedup vs baseline: 1.1245x; 1.1245x over previous
//
#include <hip/hip_runtime.h>
#include <hip/hip_bf16.h>

#define N_ROWS 32768
#define K_DIM 512
#define OUT_DIM 512
#define N_TYPES 8
#define BM 64
#define BN 256
#define BK 64
#define TPB 512             // row-tiles per type (fixed segment: 512*64 = N)

typedef __attribute__((ext_vector_type(8))) short bf16x8;
typedef __attribute__((ext_vector_type(4))) float f32x4;

__device__ inline ushort f2bf(float f) {
    __hip_bfloat16 h = __float2bfloat16(f);
    return *reinterpret_cast<ushort*>(&h);
}

__device__ inline void gload_lds16(const void* g, void* l) {
    __builtin_amdgcn_global_load_lds(
        (const __attribute__((address_space(1))) void*)g,
        (__attribute__((address_space(3))) void*)l, 16, 0, 0);
}

// meta[0..7] = per-type cursors; final value after k_fill = per-type count.
// row_ids: fixed 1-MB layout, segment t at [t*N_ROWS, ...).
__global__ void k_fill(const int* __restrict__ x_type, int* meta, int* __restrict__ row_ids) {
    __shared__ int lcnt[N_TYPES];
    __shared__ int lbase[N_TYPES];
    if (threadIdx.x < N_TYPES) lcnt[threadIdx.x] = 0;
    __syncthreads();
    int i = blockIdx.x * 256 + threadIdx.x;
    int t = x_type[i];
    int lpos = atomicAdd(&lcnt[t], 1);
    __syncthreads();
    if (threadIdx.x < N_TYPES)
        lbase[threadIdx.x] = (lcnt[threadIdx.x] > 0)
            ? atomicAdd(&meta[threadIdx.x], lcnt[threadIdx.x]) : 0;
    __syncthreads();
    row_ids[(size_t)t * N_ROWS + lbase[t] + lpos] = i;
}

// W[t][k][c] fp32 -> Wt[t][c][k] bf16 (64x64 tiles through LDS).
// Also pads row_ids[count_t, roundup64(count_t)) with -1 (replaces the 1-MB
// memset dispatch; k_wt runs after k_fill so meta is final).
__global__ void k_wt(const float* __restrict__ W, ushort* __restrict__ Wt,
                     const int* __restrict__ meta, int* __restrict__ row_ids) {
    __shared__ float tile[64][65];
    int t = blockIdx.x, kb = blockIdx.y, cb = blockIdx.z;
    if (kb == 0 && cb == 0 && threadIdx.x < 64) {
        int cnt = meta[t];
        int pad = ((cnt + 63) & ~63) - cnt;        // <= 63 slots
        if ((int)threadIdx.x < pad)
            row_ids[(size_t)t * N_ROWS + cnt + threadIdx.x] = -1;
    }
    const float* src = W + (size_t)t * K_DIM * OUT_DIM + (size_t)kb * 64 * OUT_DIM + cb * 64;
    #pragma unroll
    for (int j = 0; j < 16; ++j) {
        int idx = threadIdx.x + j * 256;
        int r = idx >> 6, c = idx & 63;
        tile[r][c] = src[(size_t)r * OUT_DIM + c];
    }
    __syncthreads();
    ushort* dst = Wt + (size_t)t * OUT_DIM * K_DIM + (size_t)(cb * 64) * K_DIM + kb * 64;
    #pragma unroll
    for (int j = 0; j < 16; ++j) {
        int idx = threadIdx.x + j * 256;
        int cc = idx >> 6, kk = idx & 63;
        dst[(size_t)cc * K_DIM + kk] = f2bf(tile[kk][cc]);
    }
}

// r14/r18 champion core, unchanged, with XCD-aware block pairing:
// blockIdx g decodes to (pair p, col c) such that both col-tiles of a pair
// land on the SAME XCD in adjacent slots (dispatch round-robins XCD by
// blockIdx%8):  x=g&7, s=g>>3, c=s&1, p=(s>>1)*8+x.  The 128-KB x panel is
// then L2-shared between the pair -> second col pass hits L2 instead of HBM.
// 64x256 tile, 8 waves of 32x64 (acc[2][4]), BK=64 single-buffered,
// LDS 40960 B, involution swizzle (0 conflicts), B via global_load_lds with
// involution on SOURCE (rule #21), thin A-stage (8 fp32->bf16/thread).
__global__ __launch_bounds__(512, 4) void k_gemm18(
    const float* __restrict__ x, const ushort* __restrict__ Wt,
    const int* __restrict__ meta, const int* __restrict__ row_ids,
    float* __restrict__ out) {

    __shared__ ushort As[BM * BK];   // 8192 B,  [row][64k], 128 B/row
    __shared__ ushort Bs[BN * BK];   // 32768 B, [col][64k], 128 B/col-row

    // ---- XCD-pair decode (bijective over 8192 blocks) ----
    int g = blockIdx.x;
    int xcd  = g & 7;
    int slot = g >> 3;
    int cpair = slot & 1;
    int p = (slot >> 1) * 8 + xcd;   // pair id in [0, 4096)

    int type = p >> 9;
    int r0 = (p & (TPB - 1)) * BM;
    if (r0 >= meta[type]) return;    // empty tile

    size_t seg = (size_t)type * N_ROWS + r0;

    int tid = threadIdx.x;
    int wave = tid >> 6, lane = tid & 63;

    int c0 = cpair * BN;
    const ushort* Wtt = Wt + (size_t)type * OUT_DIM * K_DIM + (size_t)c0 * K_DIM;

    // ---- A staging role: 8 threads/row, 8 elems (32 B fp32) each ----
    int sa_row  = tid >> 3;
    int sa_slot = tid & 7;           // 16-B bf16 granule within 128-B row
    int sa_rid  = row_ids[seg + sa_row];   // coalesced (8 thr/address)
    const float* sa_src = x + (size_t)max(sa_rid, 0) * K_DIM + sa_slot * 8;
    int sa_byte = (sa_row * 128 + sa_slot * 16) ^ ((sa_row & 7) << 4);

    // ---- B staging role: chunk = 8 cols x 128 B (1 KB); lane -> (col,pos);
    //      source granule = pos ^ (col&7)  (involution on SOURCE) ----
    int sb_colgrp = lane >> 3;                               // 0..7
    int sb_koff   = (((lane & 7) * 16) ^ (sb_colgrp << 4)) >> 1;  // elems

    int wrb = (wave >> 2) * 32;      // wave row base (0/32)
    int wcb = (wave & 3) * 64;       // wave col base (0..192)
    int lrow = lane & 15;
    int lkb16 = (lane >> 4) * 16;    // 16-B k-fragment offset

    f32x4 acc[2][4] = {};

    #pragma unroll 1
    for (int kk = 0; kk < K_DIM; kk += BK) {
        // stage B: 4 chunks/wave, 1 KB each (8 cols x 128 B)
        #pragma unroll
        for (int j = 0; j < 4; ++j) {
            int chunk = wave * 4 + j;
            int col = chunk * 8 + sb_colgrp;
            gload_lds16(Wtt + (size_t)col * K_DIM + kk + sb_koff,
                        (char*)Bs + chunk * 1024);
        }
        // stage A: load 8 fp32, convert, swizzled ds_write
        {
            ushort tmp[8] = {0, 0, 0, 0, 0, 0, 0, 0};
            if (sa_rid >= 0) {
                float4 v0 = *reinterpret_cast<const float4*>(sa_src + kk);
                float4 v1 = *reinterpret_cast<const float4*>(sa_src + kk + 4);
                tmp[0] = f2bf(v0.x); tmp[1] = f2bf(v0.y); tmp[2] = f2bf(v0.z); tmp[3] = f2bf(v0.w);
                tmp[4] = f2bf(v1.x); tmp[5] = f2bf(v1.y); tmp[6] = f2bf(v1.z); tmp[7] = f2bf(v1.w);
            }
            *reinterpret_cast<uint4*>((char*)As + sa_byte) = *reinterpret_cast<const uint4*>(tmp);
        }
        __syncthreads();

        #pragma unroll
        for (int s = 0; s < 2; ++s) {
            bf16x8 af[2], bfr[4];
            #pragma unroll
            for (int mi = 0; mi < 2; ++mi) {
                int row = wrb + mi * 16 + lrow;
                int byte = (row * 128 + s * 64 + lkb16) ^ ((row & 7) << 4);
                af[mi] = *reinterpret_cast<const bf16x8*>((const char*)As + byte);
            }
            #pragma unroll
            for (int ni = 0; ni < 4; ++ni) {
                int col = wcb + ni * 16 + lrow;
                int byte = (col * 128 + s * 64 + lkb16) ^ ((col & 7) << 4);
                bfr[ni] = *reinterpret_cast<const bf16x8*>((const char*)Bs + byte);
            }
            #pragma unroll
            for (int mi = 0; mi < 2; ++mi)
                #pragma unroll
                for (int ni = 0; ni < 4; ++ni)
                    acc[mi][ni] = __builtin_amdgcn_mfma_f32_16x16x32_bf16(
                        af[mi], bfr[ni], acc[mi][ni], 0, 0, 0);
        }
        __syncthreads();
    }

    // epilogue: D row = (lane>>4)*4 + rr, col = lane&15
    // row-ids read from global: address shared by 16 lanes -> broadcast, L2-hot
    int rgrp = (lane >> 4) * 4;
    #pragma unroll
    for (int mi = 0; mi < 2; ++mi) {
        #pragma unroll
        for (int rr = 0; rr < 4; ++rr) {
            int lr = wrb + mi * 16 + rgrp + rr;
            int gr = row_ids[seg + lr];
            if (gr >= 0) {
                float* dst = out + (size_t)gr * OUT_DIM + c0 + wcb;
                #pragma unroll
                for (int ni = 0; ni < 4; ++ni)
                    dst[ni * 16 + lrow] = acc[mi][ni][rr];
            }
        }
    }
}

extern "C" void kernel_launch(void* const* d_in, const int* in_sizes, int n_in,
                              void* d_out, int out_size, void* d_ws, size_t ws_size,
                              hipStream_t stream) {
    const float* x      = (const float*)d_in[0];
    const int*   x_type = (const int*)d_in[1];
    const float* W      = (const float*)d_in[2];
    float* out          = (float*)d_out;

    // ws layout: meta (256 B) | row_ids (8*N ints = 1 MB) | Wt (4 MB bf16)
    char* ws = (char*)d_ws;
    size_t off_rids = 256;
    size_t off_wt   = off_rids + sizeof(int) * (size_t)N_TYPES * N_ROWS;
    int* meta    = (int*)ws;
    int* row_ids = (int*)(ws + off_rids);
    ushort* Wt   = (ushort*)(ws + off_wt);

    hipMemsetAsync(meta, 0, sizeof(int) * N_TYPES, stream);
    k_fill<<<N_ROWS / 256, 256, 0, stream>>>(x_type, meta, row_ids);

    dim3 wgrid(N_TYPES, K_DIM / 64, OUT_DIM / 64);
    k_wt<<<wgrid, 256, 0, stream>>>(W, Wt, meta, row_ids);

    // 8192 blocks; XCD-pair decode inside the kernel
    k_gemm18<<<N_TYPES * TPB * 2, 512, 0, stream>>>(x, Wt, meta, row_ids, out);
}

// Round 20
// 53.382 us; speedup vs baseline: 1.1996x; 1.0668x over previous
//
#include <hip/hip_runtime.h>
#include <hip/hip_bf16.h>

#define N_ROWS 32768
#define K_DIM 512
#define OUT_DIM 512
#define N_TYPES 8
#define BM 64
#define BN 256
#define BK 64
#define NT 8                // K-steps
#define TPB 512             // row-tiles per type (fixed segment: 512*64 = N)

typedef __attribute__((ext_vector_type(8))) short bf16x8;
typedef __attribute__((ext_vector_type(4))) float f32x4;

__device__ inline ushort f2bf(float f) {
    __hip_bfloat16 h = __float2bfloat16(f);
    return *reinterpret_cast<ushort*>(&h);
}

__device__ inline void gload_lds16(const void* g, void* l) {
    __builtin_amdgcn_global_load_lds(
        (const __attribute__((address_space(1))) void*)g,
        (__attribute__((address_space(3))) void*)l, 16, 0, 0);
}

// meta[0..7] = per-type cursors; final value after k_fill = per-type count.
// row_ids: fixed 1-MB layout, segment t at [t*N_ROWS, ...).
__global__ void k_fill(const int* __restrict__ x_type, int* meta, int* __restrict__ row_ids) {
    __shared__ int lcnt[N_TYPES];
    __shared__ int lbase[N_TYPES];
    if (threadIdx.x < N_TYPES) lcnt[threadIdx.x] = 0;
    __syncthreads();
    int i = blockIdx.x * 256 + threadIdx.x;
    int t = x_type[i];
    int lpos = atomicAdd(&lcnt[t], 1);
    __syncthreads();
    if (threadIdx.x < N_TYPES)
        lbase[threadIdx.x] = (lcnt[threadIdx.x] > 0)
            ? atomicAdd(&meta[threadIdx.x], lcnt[threadIdx.x]) : 0;
    __syncthreads();
    row_ids[(size_t)t * N_ROWS + lbase[t] + lpos] = i;
}

// W[t][k][c] fp32 -> Wt[t][c][k] bf16 (64x64 tiles through LDS).
// Also pads row_ids[count_t, roundup64(count_t)) with -1 (k_wt runs after
// k_fill so meta is final).
__global__ void k_wt(const float* __restrict__ W, ushort* __restrict__ Wt,
                     const int* __restrict__ meta, int* __restrict__ row_ids) {
    __shared__ float tile[64][65];
    int t = blockIdx.x, kb = blockIdx.y, cb = blockIdx.z;
    if (kb == 0 && cb == 0 && threadIdx.x < 64) {
        int cnt = meta[t];
        int pad = ((cnt + 63) & ~63) - cnt;        // <= 63 slots
        if ((int)threadIdx.x < pad)
            row_ids[(size_t)t * N_ROWS + cnt + threadIdx.x] = -1;
    }
    const float* src = W + (size_t)t * K_DIM * OUT_DIM + (size_t)kb * 64 * OUT_DIM + cb * 64;
    #pragma unroll
    for (int j = 0; j < 16; ++j) {
        int idx = threadIdx.x + j * 256;
        int r = idx >> 6, c = idx & 63;
        tile[r][c] = src[(size_t)r * OUT_DIM + c];
    }
    __syncthreads();
    ushort* dst = Wt + (size_t)t * OUT_DIM * K_DIM + (size_t)(cb * 64) * K_DIM + kb * 64;
    #pragma unroll
    for (int j = 0; j < 16; ++j) {
        int idx = threadIdx.x + j * 256;
        int cc = idx >> 6, kk = idx & 63;
        dst[(size_t)cc * K_DIM + kk] = f2bf(tile[kk][cc]);
    }
}

// r19 champion (56.95 us) + ONE change: A-register-load software pipeline
// (T14 issue-early).  Step t+1's two float4 x-loads are issued right after
// step t's WRITE_A, BEFORE the barrier -- the mandatory pre-barrier vmcnt(0)
// drain (waiting on B's global_load_lds anyway) absorbs the A-load latency,
// so next step's convert finds data in registers.  +8 VGPR, no other change.
// XCD-pair decode: both col-tiles of a row-tile on the SAME XCD (L2-shared
// x panel -> FETCH 50 MB, r19-proven).  64x256 tile, 8 waves of 32x64
// (acc[2][4]), BK=64 single-buffered, LDS 40960 B, involution swizzle
// (0 conflicts), B via global_load_lds with involution on SOURCE (rule #21).
__global__ __launch_bounds__(512, 4) void k_gemm19(
    const float* __restrict__ x, const ushort* __restrict__ Wt,
    const int* __restrict__ meta, const int* __restrict__ row_ids,
    float* __restrict__ out) {

    __shared__ ushort As[BM * BK];   // 8192 B,  [row][64k], 128 B/row
    __shared__ ushort Bs[BN * BK];   // 32768 B, [col][64k], 128 B/col-row

    // ---- XCD-pair decode (bijective over 8192 blocks) ----
    int g = blockIdx.x;
    int xcd  = g & 7;
    int slot = g >> 3;
    int cpair = slot & 1;
    int p = (slot >> 1) * 8 + xcd;   // pair id in [0, 4096)

    int type = p >> 9;
    int r0 = (p & (TPB - 1)) * BM;
    if (r0 >= meta[type]) return;    // empty tile

    size_t seg = (size_t)type * N_ROWS + r0;

    int tid = threadIdx.x;
    int wave = tid >> 6, lane = tid & 63;

    int c0 = cpair * BN;
    const ushort* Wtt = Wt + (size_t)type * OUT_DIM * K_DIM + (size_t)c0 * K_DIM;

    // ---- A staging role: 8 threads/row, 8 elems (32 B fp32) each ----
    int sa_row  = tid >> 3;
    int sa_slot = tid & 7;           // 16-B bf16 granule within 128-B row
    int sa_rid  = row_ids[seg + sa_row];   // coalesced (8 thr/address)
    const float* sa_src = x + (size_t)max(sa_rid, 0) * K_DIM + sa_slot * 8;
    int sa_byte = (sa_row * 128 + sa_slot * 16) ^ ((sa_row & 7) << 4);

    // ---- B staging role: chunk = 8 cols x 128 B (1 KB); lane -> (col,pos);
    //      source granule = pos ^ (col&7)  (involution on SOURCE) ----
    int sb_colgrp = lane >> 3;                               // 0..7
    int sb_koff   = (((lane & 7) * 16) ^ (sb_colgrp << 4)) >> 1;  // elems

    int wrb = (wave >> 2) * 32;      // wave row base (0/32)
    int wcb = (wave & 3) * 64;       // wave col base (0..192)
    int lrow = lane & 15;
    int lkb16 = (lane >> 4) * 16;    // 16-B k-fragment offset

    f32x4 acc[2][4] = {};

    // ---- A-load pipeline prologue: issue step-0 loads ----
    float4 va0 = {0.f, 0.f, 0.f, 0.f}, va1 = {0.f, 0.f, 0.f, 0.f};
    if (sa_rid >= 0) {
        va0 = *reinterpret_cast<const float4*>(sa_src);
        va1 = *reinterpret_cast<const float4*>(sa_src + 4);
    }

    #pragma unroll 1
    for (int t8 = 0; t8 < NT; ++t8) {
        int kk = t8 * BK;
        // stage B: 4 chunks/wave, 1 KB each (8 cols x 128 B), async to LDS
        #pragma unroll
        for (int j = 0; j < 4; ++j) {
            int chunk = wave * 4 + j;
            int col = chunk * 8 + sb_colgrp;
            gload_lds16(Wtt + (size_t)col * K_DIM + kk + sb_koff,
                        (char*)Bs + chunk * 1024);
        }
        // stage A: convert prefetched regs, swizzled ds_write
        {
            ushort tmp[8] = { f2bf(va0.x), f2bf(va0.y), f2bf(va0.z), f2bf(va0.w),
                              f2bf(va1.x), f2bf(va1.y), f2bf(va1.z), f2bf(va1.w) };
            *reinterpret_cast<uint4*>((char*)As + sa_byte) = *reinterpret_cast<const uint4*>(tmp);
        }
        // issue NEXT step's A loads before the barrier: their latency hides
        // under the pre-barrier vmcnt drain + compute
        if (t8 < NT - 1 && sa_rid >= 0) {
            va0 = *reinterpret_cast<const float4*>(sa_src + kk + BK);
            va1 = *reinterpret_cast<const float4*>(sa_src + kk + BK + 4);
        }
        __syncthreads();

        #pragma unroll
        for (int s = 0; s < 2; ++s) {
            bf16x8 af[2], bfr[4];
            #pragma unroll
            for (int mi = 0; mi < 2; ++mi) {
                int row = wrb + mi * 16 + lrow;
                int byte = (row * 128 + s * 64 + lkb16) ^ ((row & 7) << 4);
                af[mi] = *reinterpret_cast<const bf16x8*>((const char*)As + byte);
            }
            #pragma unroll
            for (int ni = 0; ni < 4; ++ni) {
                int col = wcb + ni * 16 + lrow;
                int byte = (col * 128 + s * 64 + lkb16) ^ ((col & 7) << 4);
                bfr[ni] = *reinterpret_cast<const bf16x8*>((const char*)Bs + byte);
            }
            #pragma unroll
            for (int mi = 0; mi < 2; ++mi)
                #pragma unroll
                for (int ni = 0; ni < 4; ++ni)
                    acc[mi][ni] = __builtin_amdgcn_mfma_f32_16x16x32_bf16(
                        af[mi], bfr[ni], acc[mi][ni], 0, 0, 0);
        }
        __syncthreads();
    }

    // epilogue: D row = (lane>>4)*4 + rr, col = lane&15
    // row-ids from global: address shared by 16 lanes -> broadcast, L2-hot
    int rgrp = (lane >> 4) * 4;
    #pragma unroll
    for (int mi = 0; mi < 2; ++mi) {
        #pragma unroll
        for (int rr = 0; rr < 4; ++rr) {
            int lr = wrb + mi * 16 + rgrp + rr;
            int gr = row_ids[seg + lr];
            if (gr >= 0) {
                float* dst = out + (size_t)gr * OUT_DIM + c0 + wcb;
                #pragma unroll
                for (int ni = 0; ni < 4; ++ni)
                    dst[ni * 16 + lrow] = acc[mi][ni][rr];
            }
        }
    }
}

extern "C" void kernel_launch(void* const* d_in, const int* in_sizes, int n_in,
                              void* d_out, int out_size, void* d_ws, size_t ws_size,
                              hipStream_t stream) {
    const float* x      = (const float*)d_in[0];
    const int*   x_type = (const int*)d_in[1];
    const float* W      = (const float*)d_in[2];
    float* out          = (float*)d_out;

    // ws layout: meta (256 B) | row_ids (8*N ints = 1 MB) | Wt (4 MB bf16)
    char* ws = (char*)d_ws;
    size_t off_rids = 256;
    size_t off_wt   = off_rids + sizeof(int) * (size_t)N_TYPES * N_ROWS;
    int* meta    = (int*)ws;
    int* row_ids = (int*)(ws + off_rids);
    ushort* Wt   = (ushort*)(ws + off_wt);

    hipMemsetAsync(meta, 0, sizeof(int) * N_TYPES, stream);
    k_fill<<<N_ROWS / 256, 256, 0, stream>>>(x_type, meta, row_ids);

    dim3 wgrid(N_TYPES, K_DIM / 64, OUT_DIM / 64);
    k_wt<<<wgrid, 256, 0, stream>>>(W, Wt, meta, row_ids);

    // 8192 blocks; XCD-pair decode inside the kernel
    k_gemm19<<<N_TYPES * TPB * 2, 512, 0, stream>>>(x, Wt, meta, row_ids, out);
}